// Round 11
// baseline (612.156 us; speedup 1.0000x reference)
//
#include <hip/hip_runtime.h>

#define HH 4
#define FF 128
#define DD 32

typedef float f32x4 __attribute__((ext_vector_type(4)));

// ---------------- fused scatter + rel physical permute ----------------
// 16 lanes per edge: lane u copies rel[e] f-slice [u*8, u*8+8) into
// rel_s[pos]; lane u==0 allocates pos and writes packed (edge,dst).
// Read side sequential (full BW); write side is the single unavoidable
// random-row pass, now a pure copy with maximal MLP and no dependent compute.

__global__ __launch_bounds__(256) void scatter_kernel(
    const int* __restrict__ src, const int* __restrict__ dst,
    const float* __restrict__ rel, int* __restrict__ cursor,
    int2* __restrict__ ed, float* __restrict__ rel_s, int E) {
    int tid = threadIdx.x;
    int e = blockIdx.x * 16 + (tid >> 4);
    if (e >= E) return;
    int u = tid & 15;
    int pos = 0;
    if (u == 0) {
        pos = atomicAdd(&cursor[src[e]], 1);
        long long pack = (unsigned)e | ((long long)dst[e] << 32);   // .x=e, .y=dst
        __builtin_nontemporal_store(pack, (long long*)&ed[pos]);
    }
    int lane = tid & 63;
    pos = __shfl(pos, lane & ~15, 64);
    const f32x4* rp = (const f32x4*)(rel + (size_t)e * FF + u * 8);
    f32x4 a = __builtin_nontemporal_load(rp);
    f32x4 b = __builtin_nontemporal_load(rp + 1);
    f32x4* wp = (f32x4*)(rel_s + (size_t)pos * FF + u * 8);
    __builtin_nontemporal_store(a, wp);
    __builtin_nontemporal_store(b, wp + 1);
}

// ---------------- fused: q+k projection + histogram ----------------

__global__ __launch_bounds__(256) void qk_hist_kernel(
    const float* __restrict__ feat, const float* __restrict__ wq,
    const float* __restrict__ wk, float* __restrict__ q,
    float* __restrict__ k, int N,
    const int* __restrict__ src, int* __restrict__ counts, int E, int QKB) {
    __shared__ float fs[32 * FF];
    int bid = blockIdx.x;
    if (bid >= QKB) {           // ---- histogram role ----
        int i = ((bid - QKB) * 256 + threadIdx.x) * 4;
        if (i + 3 < E) {
            int4 v = *(const int4*)(src + i);
            atomicAdd(&counts[v.x], 1);
            atomicAdd(&counts[v.y], 1);
            atomicAdd(&counts[v.z], 1);
            atomicAdd(&counts[v.w], 1);
        } else {
            for (; i < E; ++i) atomicAdd(&counts[src[i]], 1);
        }
        return;
    }
    // ---- qk role: each thread computes BOTH q and k for 16 entities ----
    int n0 = bid * 32;
    int nb = N - n0; if (nb > 32) nb = 32;
    const float4* s4 = (const float4*)(feat + (size_t)n0 * FF);
    int nf4 = nb * FF / 4;
    for (int i = threadIdx.x; i < nf4; i += 256) ((float4*)fs)[i] = s4[i];
    __syncthreads();

    int half = threadIdx.x >> 7;
    int o    = threadIdx.x & 127;
    int h = o >> 5, d = o & 31;
    const float* wqp = wq + ((size_t)h * FF) * DD + d;
    const float* wkp = wk + ((size_t)h * FF) * DD + d;

    float accq[16], acck[16];
#pragma unroll
    for (int e = 0; e < 16; ++e) { accq[e] = 0.f; acck[e] = 0.f; }
    for (int f = 0; f < FF; f += 4) {
        float wq0 = wqp[(f + 0) * DD], wq1 = wqp[(f + 1) * DD];
        float wq2 = wqp[(f + 2) * DD], wq3 = wqp[(f + 3) * DD];
        float wk0 = wkp[(f + 0) * DD], wk1 = wkp[(f + 1) * DD];
        float wk2 = wkp[(f + 2) * DD], wk3 = wkp[(f + 3) * DD];
#pragma unroll
        for (int e = 0; e < 16; ++e) {
            float4 fv = *(const float4*)&fs[(half * 16 + e) * FF + f];
            accq[e] += fv.x * wq0 + fv.y * wq1 + fv.z * wq2 + fv.w * wq3;
            acck[e] += fv.x * wk0 + fv.y * wk1 + fv.z * wk2 + fv.w * wk3;
        }
    }
    int ecnt = nb - half * 16; if (ecnt < 0) ecnt = 0; if (ecnt > 16) ecnt = 16;
    for (int e = 0; e < ecnt; ++e) {
        size_t n = (size_t)(n0 + half * 16 + e);
        q[(n * HH + h) * DD + d] = accq[e];
        k[(n * HH + h) * DD + d] = acck[e];
    }
}

// ---------------- fused: kk projection + group-offset alloc ----------------

__global__ __launch_bounds__(256) void kk_alloc_kernel(
    const float* __restrict__ kbuf, const float* __restrict__ wk,
    float* __restrict__ kkout, int N,
    const int* __restrict__ counts, int* __restrict__ startb,
    int* __restrict__ cursor, int* __restrict__ gcur, int KKB) {
    __shared__ float ks[16 * FF];
    int bid = blockIdx.x;
    if (bid >= KKB) {           // ---- alloc role: wave scan + one atomic ----
        int sid = (bid - KKB) * 256 + threadIdx.x;
        int lane = threadIdx.x & 63;
        int cnt = (sid < N) ? counts[sid] : 0;
        int incl = cnt;
#pragma unroll
        for (int off = 1; off < 64; off <<= 1) {
            int y = __shfl_up(incl, off, 64);
            if (lane >= off) incl += y;
        }
        int total = __shfl(incl, 63, 64);
        int base = 0;
        if (lane == 63) base = atomicAdd(gcur, total);
        base = __shfl(base, 63, 64);
        if (sid < N) {
            int st = base + incl - cnt;
            startb[sid] = st;
            cursor[sid] = st;
        }
        return;
    }
    // ---- kk role ----
    int n0 = bid * 16;
    int nb = N - n0; if (nb > 16) nb = 16;
    const float4* s4 = (const float4*)(kbuf + (size_t)n0 * FF);
    int nf4 = nb * FF / 4;
    for (int i = threadIdx.x; i < nf4; i += 256) ((float4*)ks)[i] = s4[i];
    __syncthreads();

    int o = threadIdx.x;
    int h1 = o >> 7, f1 = o & 127;
    int h2 = h1 + 2;
    const float* w1 = wk + ((size_t)h1 * FF + f1) * DD;
    const float* w2 = wk + ((size_t)h2 * FF + f1) * DD;

    float acc1[16], acc2[16];
#pragma unroll
    for (int e = 0; e < 16; ++e) { acc1[e] = 0.f; acc2[e] = 0.f; }
    for (int d = 0; d < DD; d += 4) {
        float4 wv1 = *(const float4*)&w1[d];
        float4 wv2 = *(const float4*)&w2[d];
#pragma unroll
        for (int e = 0; e < 16; ++e) {
            float4 k1 = *(const float4*)&ks[e * FF + h1 * DD + d];
            float4 k2 = *(const float4*)&ks[e * FF + h2 * DD + d];
            acc1[e] += k1.x * wv1.x + k1.y * wv1.y + k1.z * wv1.z + k1.w * wv1.w;
            acc2[e] += k2.x * wv2.x + k2.y * wv2.y + k2.z * wv2.z + k2.w * wv2.w;
        }
    }
    for (int e = 0; e < nb; ++e) {
        kkout[((size_t)(n0 + e) * HH + h1) * FF + f1] = acc1[e];
        kkout[((size_t)(n0 + e) * HH + h2) * FF + f1] = acc2[e];
    }
}

// ---------------- group kernel v11: sequential rel_s read ----------------

__device__ __forceinline__ void score_row(   // slow-path helper
    const float* __restrict__ rel_s, const float* __restrict__ k,
    int row, int dd, int t,
    const float4* kkA, const float4* kkB, const float2* qv, float* ev) {
    const float* rp = rel_s + (size_t)row * FF + t * 8;
    f32x4 r0 = __builtin_nontemporal_load((const f32x4*)rp);
    f32x4 r1 = __builtin_nontemporal_load((const f32x4*)(rp + 4));
#pragma unroll
    for (int h = 0; h < HH; ++h) {
        float2 kv = *(const float2*)(k + ((size_t)dd * HH + h) * DD + t * 2);
        float a = r0.x * kkA[h].x + r0.y * kkA[h].y + r0.z * kkA[h].z + r0.w * kkA[h].w
                + r1.x * kkB[h].x + r1.y * kkB[h].y + r1.z * kkB[h].z + r1.w * kkB[h].w
                + qv[h].x * kv.x + qv[h].y * kv.y;
#pragma unroll
        for (int off = 1; off < 16; off <<= 1) a += __shfl_xor(a, off, 64);
        ev[h] = a >= 0.f ? a : 0.01f * a;
    }
}

__global__ __launch_bounds__(256) void group_kernel(
    const float* __restrict__ rel_s, const int2* __restrict__ ed,
    const float* __restrict__ q, const float* __restrict__ k,
    const float* __restrict__ kk, const int* __restrict__ start,
    const int* __restrict__ counts, float* __restrict__ out, int N) {
    __shared__ __align__(16) float e_buf_all[4][128][4];
    int wid = threadIdx.x >> 6;
    int s = blockIdx.x * 4 + wid;
    if (s >= N) return;
    int cnt = counts[s];
    if (cnt == 0) return;
    int base = start[s];
    int lane = threadIdx.x & 63;
    int g = lane >> 4, t = lane & 15;
    int hsel = ((t & 1) << 1) | ((t & 2) >> 1);
    float (*e_buf)[4] = e_buf_all[wid];

    float4 kkA[HH], kkB[HH];
    float2 qv[HH];
    const float* kkbase = kk + (size_t)s * (HH * FF) + t * 8;
    const float* qbase  = q  + (size_t)s * (HH * DD) + t * 2;
#pragma unroll
    for (int h = 0; h < HH; ++h) {
        kkA[h] = *(const float4*)(kkbase + h * FF);
        kkB[h] = *(const float4*)(kkbase + h * FF + 4);
        qv[h]  = *(const float2*)(qbase + h * DD);
    }

    float mloc = -INFINITY;
    bool fast = (cnt <= 128);

    for (int c0 = 0; c0 < cnt; c0 += 64) {
        int nc = min(cnt - c0, 64);
        int dv = 0;
        if (lane < nc) dv = ed[base + c0 + lane].y;
        for (int j0 = 0; j0 < nc; j0 += 4) {
            int idx = j0 + g;
            int sel = idx < nc ? idx : 0;
            int dd  = __shfl(dv, sel, 64);
            // rel_s row index is DIRECT (sorted order) -> sequential stream
            const float* rp = rel_s + (size_t)(base + c0 + sel) * FF + t * 8;
            f32x4 r0 = __builtin_nontemporal_load((const f32x4*)rp);
            f32x4 r1 = __builtin_nontemporal_load((const f32x4*)(rp + 4));
            float p[HH];
#pragma unroll
            for (int h = 0; h < HH; ++h) {
                float2 kv = *(const float2*)(k + ((size_t)dd * HH + h) * DD + t * 2);
                p[h] = r0.x * kkA[h].x + r0.y * kkA[h].y + r0.z * kkA[h].z + r0.w * kkA[h].w
                     + r1.x * kkB[h].x + r1.y * kkB[h].y + r1.z * kkB[h].z + r1.w * kkB[h].w
                     + qv[h].x * kv.x + qv[h].y * kv.y;
            }
            // 5-shfl multi-head butterfly
            float sx = (t & 1) ? p[0] : p[2];
            float sy = (t & 1) ? p[1] : p[3];
            float rx = __shfl_xor(sx, 1, 64);
            float ry = __shfl_xor(sy, 1, 64);
            float a0 = ((t & 1) ? p[2] : p[0]) + rx;
            float a1 = ((t & 1) ? p[3] : p[1]) + ry;
            float sz = (t & 2) ? a0 : a1;
            float rz = __shfl_xor(sz, 2, 64);
            float e = ((t & 2) ? a1 : a0) + rz;
            e += __shfl_xor(e, 4, 64);
            e += __shfl_xor(e, 8, 64);
            e = e >= 0.f ? e : 0.01f * e;              // leaky_relu(0.01)
            if (idx < nc) {
                mloc = fmaxf(mloc, e);
                if (fast && t < 4) e_buf[c0 + idx][hsel] = e;
            }
        }
    }
    mloc = fmaxf(mloc, __shfl_xor(mloc, 16, 64));
    mloc = fmaxf(mloc, __shfl_xor(mloc, 32, 64));
    float m[HH];
    m[0] = __shfl(mloc, 0, 64);
    m[1] = __shfl(mloc, 2, 64);
    m[2] = __shfl(mloc, 1, 64);
    m[3] = __shfl(mloc, 3, 64);

    if (fast) {
        int i0 = lane, i1 = lane + 64;
        float ex0[HH] = {0.f, 0.f, 0.f, 0.f}, ex1[HH] = {0.f, 0.f, 0.f, 0.f};
        if (i0 < cnt) {
            float4 ev = *(const float4*)e_buf[i0];
            ex0[0] = __expf(ev.x - m[0]); ex0[1] = __expf(ev.y - m[1]);
            ex0[2] = __expf(ev.z - m[2]); ex0[3] = __expf(ev.w - m[3]);
        }
        if (i1 < cnt) {
            float4 ev = *(const float4*)e_buf[i1];
            ex1[0] = __expf(ev.x - m[0]); ex1[1] = __expf(ev.y - m[1]);
            ex1[2] = __expf(ev.z - m[2]); ex1[3] = __expf(ev.w - m[3]);
        }
        float rl[HH];
#pragma unroll
        for (int h = 0; h < HH; ++h) {
            float v = ex0[h] + ex1[h];
#pragma unroll
            for (int off = 1; off < 64; off <<= 1) v += __shfl_xor(v, off, 64);
            rl[h] = 1.0f / v;
        }
        if (i0 < cnt)
            out[ed[base + i0].x] = 0.25f * (ex0[0]*rl[0] + ex0[1]*rl[1] + ex0[2]*rl[2] + ex0[3]*rl[3]);
        if (i1 < cnt)
            out[ed[base + i1].x] = 0.25f * (ex1[0]*rl[0] + ex1[1]*rl[1] + ex1[2]*rl[2] + ex1[3]*rl[3]);
    } else {
        // slow path (cnt > 128): recompute; practically never taken
        float lacc[HH] = {0.f, 0.f, 0.f, 0.f};
        for (int c0 = 0; c0 < cnt; c0 += 64) {
            int nc = min(cnt - c0, 64);
            int dv = 0;
            if (lane < nc) dv = ed[base + c0 + lane].y;
            for (int j0 = 0; j0 < nc; j0 += 4) {
                int idx = j0 + g;
                int sel = idx < nc ? idx : 0;
                int dd  = __shfl(dv, sel, 64);
                float ev[HH];
                score_row(rel_s, k, base + c0 + sel, dd, t, kkA, kkB, qv, ev);
                if (idx < nc && t == 0) {
#pragma unroll
                    for (int h = 0; h < HH; ++h) lacc[h] += __expf(ev[h] - m[h]);
                }
            }
        }
        float rl[HH];
#pragma unroll
        for (int h = 0; h < HH; ++h) {
            float v = lacc[h];
#pragma unroll
            for (int off = 1; off < 64; off <<= 1) v += __shfl_xor(v, off, 64);
            rl[h] = 1.0f / v;
        }
        for (int c0 = 0; c0 < cnt; c0 += 64) {
            int nc = min(cnt - c0, 64);
            int pv = 0, dv = 0;
            if (lane < nc) { int2 pd = ed[base + c0 + lane]; pv = pd.x; dv = pd.y; }
            for (int j0 = 0; j0 < nc; j0 += 4) {
                int idx = j0 + g;
                int sel = idx < nc ? idx : 0;
                int e_i = __shfl(pv, sel, 64);
                int dd  = __shfl(dv, sel, 64);
                float ev[HH];
                score_row(rel_s, k, base + c0 + sel, dd, t, kkA, kkB, qv, ev);
                if (idx < nc && t == 0) {
                    float a = __expf(ev[0]-m[0])*rl[0] + __expf(ev[1]-m[1])*rl[1]
                            + __expf(ev[2]-m[2])*rl[2] + __expf(ev[3]-m[3])*rl[3];
                    out[e_i] = 0.25f * a;
                }
            }
        }
    }
}

extern "C" void kernel_launch(void* const* d_in, const int* in_sizes, int n_in,
                              void* d_out, int out_size, void* d_ws, size_t ws_size,
                              hipStream_t stream) {
    const float* feat = (const float*)d_in[0];   // (N,1,F)
    const float* rel  = (const float*)d_in[1];   // (E,1,F)
    const int*   src  = (const int*)d_in[2];
    const int*   dst  = (const int*)d_in[3];
    const float* wq   = (const float*)d_in[4];   // (H,F,D)
    const float* wk   = (const float*)d_in[5];
    float* out = (float*)d_out;

    const int N = in_sizes[0] / FF;
    const int E = in_sizes[2];

    // ws layout (~674 MB; ws is ~2 GB). rel_s first for 16B alignment.
    float* rel_s  = (float*)d_ws;                     // E*FF (sorted rel copy)
    float* q      = rel_s + (size_t)E * FF;           // N*H*D
    float* k      = q  + (size_t)N * HH * DD;         // N*H*D
    float* kk     = k  + (size_t)N * HH * DD;         // N*H*F
    int*   counts = (int*)(kk + (size_t)N * HH * FF); // N
    int*   gcur   = counts + N;                       // 1 (+1 pad for ed align)
    int*   start  = gcur + 2;                         // N
    int*   cursor = start + N;                        // N
    int2*  ed     = (int2*)(cursor + N);              // E (edge,dst)

    int nb  = (N + 255) / 256;
    int QKB = (N + 31) / 32;
    int HB  = (E + 1023) / 1024;
    int KKB = (N + 15) / 16;

    hipMemsetAsync(counts, 0, (size_t)(N + 2) * sizeof(int), stream);
    qk_hist_kernel<<<QKB + HB, 256, 0, stream>>>(feat, wq, wk, q, k, N, src, counts, E, QKB);
    kk_alloc_kernel<<<KKB + nb, 256, 0, stream>>>(k, wk, kk, N, counts, start, cursor, gcur, KKB);
    scatter_kernel<<<(E + 15) / 16, 256, 0, stream>>>(src, dst, rel, cursor, ed, rel_s, E);
    group_kernel<<<(N + 3) / 4, 256, 0, stream>>>(rel_s, ed, q, k, kk, start, counts, out, N);
}

// Round 12
// 389.788 us; speedup vs baseline: 1.5705x; 1.5705x over previous
//
#include <hip/hip_runtime.h>

#define HH 4
#define FF 128
#define DD 32

typedef float f32x4 __attribute__((ext_vector_type(4)));
typedef _Float16 h16x4 __attribute__((ext_vector_type(4)));
typedef _Float16 h16x2 __attribute__((ext_vector_type(2)));

// ---------------- scatter (sort) ----------------

__global__ void scatter_kernel(const int* __restrict__ src, const int* __restrict__ dst,
                               int* __restrict__ cursor, int2* __restrict__ ed, int E) {
    int i = blockIdx.x * blockDim.x + threadIdx.x;
    if (i >= E) return;
    int s = src[i];
    int pos = atomicAdd(&cursor[s], 1);
    long long pack = (unsigned)i | ((long long)dst[i] << 32);   // .x=i, .y=dst (LE)
    __builtin_nontemporal_store(pack, (long long*)&ed[pos]);
}

// ---------------- fused: q+k projection (fp16 out) + histogram ----------------

__global__ __launch_bounds__(256) void qk_hist_kernel(
    const float* __restrict__ feat, const float* __restrict__ wq,
    const float* __restrict__ wk, _Float16* __restrict__ q,
    _Float16* __restrict__ k, int N,
    const int* __restrict__ src, int* __restrict__ counts, int E, int QKB) {
    __shared__ float fs[32 * FF];
    int bid = blockIdx.x;
    if (bid >= QKB) {           // ---- histogram role ----
        int i = ((bid - QKB) * 256 + threadIdx.x) * 4;
        if (i + 3 < E) {
            int4 v = *(const int4*)(src + i);
            atomicAdd(&counts[v.x], 1);
            atomicAdd(&counts[v.y], 1);
            atomicAdd(&counts[v.z], 1);
            atomicAdd(&counts[v.w], 1);
        } else {
            for (; i < E; ++i) atomicAdd(&counts[src[i]], 1);
        }
        return;
    }
    // ---- qk role: each thread computes BOTH q and k for 16 entities ----
    int n0 = bid * 32;
    int nb = N - n0; if (nb > 32) nb = 32;
    const float4* s4 = (const float4*)(feat + (size_t)n0 * FF);
    int nf4 = nb * FF / 4;
    for (int i = threadIdx.x; i < nf4; i += 256) ((float4*)fs)[i] = s4[i];
    __syncthreads();

    int half = threadIdx.x >> 7;
    int o    = threadIdx.x & 127;
    int h = o >> 5, d = o & 31;
    const float* wqp = wq + ((size_t)h * FF) * DD + d;
    const float* wkp = wk + ((size_t)h * FF) * DD + d;

    float accq[16], acck[16];
#pragma unroll
    for (int e = 0; e < 16; ++e) { accq[e] = 0.f; acck[e] = 0.f; }
    for (int f = 0; f < FF; f += 4) {
        float wq0 = wqp[(f + 0) * DD], wq1 = wqp[(f + 1) * DD];
        float wq2 = wqp[(f + 2) * DD], wq3 = wqp[(f + 3) * DD];
        float wk0 = wkp[(f + 0) * DD], wk1 = wkp[(f + 1) * DD];
        float wk2 = wkp[(f + 2) * DD], wk3 = wkp[(f + 3) * DD];
#pragma unroll
        for (int e = 0; e < 16; ++e) {
            float4 fv = *(const float4*)&fs[(half * 16 + e) * FF + f];
            accq[e] += fv.x * wq0 + fv.y * wq1 + fv.z * wq2 + fv.w * wq3;
            acck[e] += fv.x * wk0 + fv.y * wk1 + fv.z * wk2 + fv.w * wk3;
        }
    }
    int ecnt = nb - half * 16; if (ecnt < 0) ecnt = 0; if (ecnt > 16) ecnt = 16;
    for (int e = 0; e < ecnt; ++e) {
        size_t n = (size_t)(n0 + half * 16 + e);
        q[(n * HH + h) * DD + d] = (_Float16)accq[e];
        k[(n * HH + h) * DD + d] = (_Float16)acck[e];
    }
}

// ---------------- fused: kk projection (fp16 in/out) + group-offset alloc ----------------

__global__ __launch_bounds__(256) void kk_alloc_kernel(
    const _Float16* __restrict__ kbuf, const float* __restrict__ wk,
    _Float16* __restrict__ kkout, int N,
    const int* __restrict__ counts, int* __restrict__ startb,
    int* __restrict__ cursor, int* __restrict__ gcur, int KKB) {
    __shared__ float ks[16 * FF];
    int bid = blockIdx.x;
    if (bid >= KKB) {           // ---- alloc role: wave scan + one atomic ----
        int sid = (bid - KKB) * 256 + threadIdx.x;
        int lane = threadIdx.x & 63;
        int cnt = (sid < N) ? counts[sid] : 0;
        int incl = cnt;
#pragma unroll
        for (int off = 1; off < 64; off <<= 1) {
            int y = __shfl_up(incl, off, 64);
            if (lane >= off) incl += y;
        }
        int total = __shfl(incl, 63, 64);
        int base = 0;
        if (lane == 63) base = atomicAdd(gcur, total);
        base = __shfl(base, 63, 64);
        if (sid < N) {
            int st = base + incl - cnt;
            startb[sid] = st;
            cursor[sid] = st;
        }
        return;
    }
    // ---- kk role: stage fp16 k -> fp32 LDS ----
    int n0 = bid * 16;
    int nb = N - n0; if (nb > 16) nb = 16;
    const h16x4* s4 = (const h16x4*)(kbuf + (size_t)n0 * FF);
    int nh4 = nb * FF / 4;
    for (int i = threadIdx.x; i < nh4; i += 256) {
        h16x4 v = s4[i];
        ((float4*)ks)[i] = make_float4((float)v.x, (float)v.y, (float)v.z, (float)v.w);
    }
    __syncthreads();

    int o = threadIdx.x;
    int h1 = o >> 7, f1 = o & 127;
    int h2 = h1 + 2;
    const float* w1 = wk + ((size_t)h1 * FF + f1) * DD;
    const float* w2 = wk + ((size_t)h2 * FF + f1) * DD;

    float acc1[16], acc2[16];
#pragma unroll
    for (int e = 0; e < 16; ++e) { acc1[e] = 0.f; acc2[e] = 0.f; }
    for (int d = 0; d < DD; d += 4) {
        float4 wv1 = *(const float4*)&w1[d];
        float4 wv2 = *(const float4*)&w2[d];
#pragma unroll
        for (int e = 0; e < 16; ++e) {
            float4 k1 = *(const float4*)&ks[e * FF + h1 * DD + d];
            float4 k2 = *(const float4*)&ks[e * FF + h2 * DD + d];
            acc1[e] += k1.x * wv1.x + k1.y * wv1.y + k1.z * wv1.z + k1.w * wv1.w;
            acc2[e] += k2.x * wv2.x + k2.y * wv2.y + k2.z * wv2.z + k2.w * wv2.w;
        }
    }
    for (int e = 0; e < nb; ++e) {
        kkout[((size_t)(n0 + e) * HH + h1) * FF + f1] = (_Float16)acc1[e];
        kkout[((size_t)(n0 + e) * HH + h2) * FF + f1] = (_Float16)acc2[e];
    }
}

// ---------------- group kernel v12: r10 structure, fp16 k/kk/q ----------------

__device__ __forceinline__ void score_row(   // slow-path helper
    const float* __restrict__ rel, const _Float16* __restrict__ k,
    int e_i, int dd, int t,
    const float4* kkA, const float4* kkB, const float2* qv, float* ev) {
    const float* rp = rel + (size_t)e_i * FF + t * 8;
    f32x4 r0 = __builtin_nontemporal_load((const f32x4*)rp);
    f32x4 r1 = __builtin_nontemporal_load((const f32x4*)(rp + 4));
#pragma unroll
    for (int h = 0; h < HH; ++h) {
        h16x2 kvh = *(const h16x2*)(k + ((size_t)dd * HH + h) * DD + t * 2);
        float a = r0.x * kkA[h].x + r0.y * kkA[h].y + r0.z * kkA[h].z + r0.w * kkA[h].w
                + r1.x * kkB[h].x + r1.y * kkB[h].y + r1.z * kkB[h].z + r1.w * kkB[h].w
                + qv[h].x * (float)kvh.x + qv[h].y * (float)kvh.y;
#pragma unroll
        for (int off = 1; off < 16; off <<= 1) a += __shfl_xor(a, off, 64);
        ev[h] = a >= 0.f ? a : 0.01f * a;
    }
}

__global__ __launch_bounds__(256) void group_kernel(
    const float* __restrict__ rel, const int2* __restrict__ ed,
    const _Float16* __restrict__ q, const _Float16* __restrict__ k,
    const _Float16* __restrict__ kk, const int* __restrict__ start,
    const int* __restrict__ counts, float* __restrict__ out, int N) {
    __shared__ __align__(16) float e_buf_all[4][128][4];
    int wid = threadIdx.x >> 6;
    int s = blockIdx.x * 4 + wid;
    if (s >= N) return;
    int cnt = counts[s];
    if (cnt == 0) return;
    int base = start[s];
    int lane = threadIdx.x & 63;
    int g = lane >> 4, t = lane & 15;
    int hsel = ((t & 1) << 1) | ((t & 2) >> 1);
    float (*e_buf)[4] = e_buf_all[wid];

    float4 kkA[HH], kkB[HH];
    float2 qv[HH];
    const _Float16* kkbase = kk + (size_t)s * (HH * FF) + t * 8;
    const _Float16* qbase  = q  + (size_t)s * (HH * DD) + t * 2;
#pragma unroll
    for (int h = 0; h < HH; ++h) {
        h16x4 a = *(const h16x4*)(kkbase + h * FF);
        h16x4 b = *(const h16x4*)(kkbase + h * FF + 4);
        kkA[h] = make_float4((float)a.x, (float)a.y, (float)a.z, (float)a.w);
        kkB[h] = make_float4((float)b.x, (float)b.y, (float)b.z, (float)b.w);
        h16x2 qh = *(const h16x2*)(qbase + h * DD);
        qv[h] = make_float2((float)qh.x, (float)qh.y);
    }

    float mloc = -INFINITY;
    bool fast = (cnt <= 128);

    for (int c0 = 0; c0 < cnt; c0 += 64) {
        int nc = min(cnt - c0, 64);
        int pv = 0, dv = 0;
        if (lane < nc) { int2 pd = ed[base + c0 + lane]; pv = pd.x; dv = pd.y; }
        for (int j0 = 0; j0 < nc; j0 += 4) {
            int idx = j0 + g;
            int sel = idx < nc ? idx : 0;
            int e_i = __shfl(pv, sel, 64);
            int dd  = __shfl(dv, sel, 64);
            const float* rp = rel + (size_t)e_i * FF + t * 8;
            f32x4 r0 = __builtin_nontemporal_load((const f32x4*)rp);
            f32x4 r1 = __builtin_nontemporal_load((const f32x4*)(rp + 4));
            float p[HH];
#pragma unroll
            for (int h = 0; h < HH; ++h) {
                h16x2 kvh = *(const h16x2*)(k + ((size_t)dd * HH + h) * DD + t * 2);
                p[h] = r0.x * kkA[h].x + r0.y * kkA[h].y + r0.z * kkA[h].z + r0.w * kkA[h].w
                     + r1.x * kkB[h].x + r1.y * kkB[h].y + r1.z * kkB[h].z + r1.w * kkB[h].w
                     + qv[h].x * (float)kvh.x + qv[h].y * (float)kvh.y;
            }
            // 5-shfl multi-head butterfly
            float sx = (t & 1) ? p[0] : p[2];
            float sy = (t & 1) ? p[1] : p[3];
            float rx = __shfl_xor(sx, 1, 64);
            float ry = __shfl_xor(sy, 1, 64);
            float a0 = ((t & 1) ? p[2] : p[0]) + rx;
            float a1 = ((t & 1) ? p[3] : p[1]) + ry;
            float sz = (t & 2) ? a0 : a1;
            float rz = __shfl_xor(sz, 2, 64);
            float e = ((t & 2) ? a1 : a0) + rz;
            e += __shfl_xor(e, 4, 64);
            e += __shfl_xor(e, 8, 64);
            e = e >= 0.f ? e : 0.01f * e;              // leaky_relu(0.01)
            if (idx < nc) {
                mloc = fmaxf(mloc, e);
                if (fast && t < 4) e_buf[c0 + idx][hsel] = e;
            }
        }
    }
    mloc = fmaxf(mloc, __shfl_xor(mloc, 16, 64));
    mloc = fmaxf(mloc, __shfl_xor(mloc, 32, 64));
    float m[HH];
    m[0] = __shfl(mloc, 0, 64);
    m[1] = __shfl(mloc, 2, 64);
    m[2] = __shfl(mloc, 1, 64);
    m[3] = __shfl(mloc, 3, 64);

    if (fast) {
        int i0 = lane, i1 = lane + 64;
        float ex0[HH] = {0.f, 0.f, 0.f, 0.f}, ex1[HH] = {0.f, 0.f, 0.f, 0.f};
        if (i0 < cnt) {
            float4 ev = *(const float4*)e_buf[i0];
            ex0[0] = __expf(ev.x - m[0]); ex0[1] = __expf(ev.y - m[1]);
            ex0[2] = __expf(ev.z - m[2]); ex0[3] = __expf(ev.w - m[3]);
        }
        if (i1 < cnt) {
            float4 ev = *(const float4*)e_buf[i1];
            ex1[0] = __expf(ev.x - m[0]); ex1[1] = __expf(ev.y - m[1]);
            ex1[2] = __expf(ev.z - m[2]); ex1[3] = __expf(ev.w - m[3]);
        }
        float rl[HH];
#pragma unroll
        for (int h = 0; h < HH; ++h) {
            float v = ex0[h] + ex1[h];
#pragma unroll
            for (int off = 1; off < 64; off <<= 1) v += __shfl_xor(v, off, 64);
            rl[h] = 1.0f / v;
        }
        if (i0 < cnt)
            out[ed[base + i0].x] = 0.25f * (ex0[0]*rl[0] + ex0[1]*rl[1] + ex0[2]*rl[2] + ex0[3]*rl[3]);
        if (i1 < cnt)
            out[ed[base + i1].x] = 0.25f * (ex1[0]*rl[0] + ex1[1]*rl[1] + ex1[2]*rl[2] + ex1[3]*rl[3]);
    } else {
        // slow path (cnt > 128): recompute; practically never taken
        float lacc[HH] = {0.f, 0.f, 0.f, 0.f};
        for (int c0 = 0; c0 < cnt; c0 += 64) {
            int nc = min(cnt - c0, 64);
            int pv = 0, dv = 0;
            if (lane < nc) { int2 pd = ed[base + c0 + lane]; pv = pd.x; dv = pd.y; }
            for (int j0 = 0; j0 < nc; j0 += 4) {
                int idx = j0 + g;
                int sel = idx < nc ? idx : 0;
                int e_i = __shfl(pv, sel, 64);
                int dd  = __shfl(dv, sel, 64);
                float ev[HH];
                score_row(rel, k, e_i, dd, t, kkA, kkB, qv, ev);
                if (idx < nc && t == 0) {
#pragma unroll
                    for (int h = 0; h < HH; ++h) lacc[h] += __expf(ev[h] - m[h]);
                }
            }
        }
        float rl[HH];
#pragma unroll
        for (int h = 0; h < HH; ++h) {
            float v = lacc[h];
#pragma unroll
            for (int off = 1; off < 64; off <<= 1) v += __shfl_xor(v, off, 64);
            rl[h] = 1.0f / v;
        }
        for (int c0 = 0; c0 < cnt; c0 += 64) {
            int nc = min(cnt - c0, 64);
            int pv = 0, dv = 0;
            if (lane < nc) { int2 pd = ed[base + c0 + lane]; pv = pd.x; dv = pd.y; }
            for (int j0 = 0; j0 < nc; j0 += 4) {
                int idx = j0 + g;
                int sel = idx < nc ? idx : 0;
                int e_i = __shfl(pv, sel, 64);
                int dd  = __shfl(dv, sel, 64);
                float ev[HH];
                score_row(rel, k, e_i, dd, t, kkA, kkB, qv, ev);
                if (idx < nc && t == 0) {
                    float a = __expf(ev[0]-m[0])*rl[0] + __expf(ev[1]-m[1])*rl[1]
                            + __expf(ev[2]-m[2])*rl[2] + __expf(ev[3]-m[3])*rl[3];
                    out[e_i] = 0.25f * a;
                }
            }
        }
    }
}

extern "C" void kernel_launch(void* const* d_in, const int* in_sizes, int n_in,
                              void* d_out, int out_size, void* d_ws, size_t ws_size,
                              hipStream_t stream) {
    const float* feat = (const float*)d_in[0];   // (N,1,F)
    const float* rel  = (const float*)d_in[1];   // (E,1,F)
    const int*   src  = (const int*)d_in[2];
    const int*   dst  = (const int*)d_in[3];
    const float* wq   = (const float*)d_in[4];   // (H,F,D)
    const float* wk   = (const float*)d_in[5];
    float* out = (float*)d_out;

    const int N = in_sizes[0] / FF;
    const int E = in_sizes[2];

    // ws layout: fp16 q/k/kk (halved), then ints, then ed pairs
    _Float16* q   = (_Float16*)d_ws;                  // N*H*D halves
    _Float16* k   = q  + (size_t)N * HH * DD;         // N*H*D halves
    _Float16* kk  = k  + (size_t)N * HH * DD;         // N*H*F halves
    int* counts   = (int*)(kk + (size_t)N * HH * FF); // N
    int* gcur     = counts + N;                       // 1 (+1 pad)
    int* start    = gcur + 2;                         // N
    int* cursor   = start + N;                        // N
    int2* ed      = (int2*)(cursor + N);              // E (edge,dst)

    int nb  = (N + 255) / 256;
    int QKB = (N + 31) / 32;
    int HB  = (E + 1023) / 1024;
    int KKB = (N + 15) / 16;

    hipMemsetAsync(counts, 0, (size_t)(N + 2) * sizeof(int), stream);
    qk_hist_kernel<<<QKB + HB, 256, 0, stream>>>(feat, wq, wk, q, k, N, src, counts, E, QKB);
    kk_alloc_kernel<<<KKB + nb, 256, 0, stream>>>(k, wk, kk, N, counts, start, cursor, gcur, KKB);
    scatter_kernel<<<(E + 255) / 256, 256, 0, stream>>>(src, dst, cursor, ed, E);
    group_kernel<<<(N + 3) / 4, 256, 0, stream>>>(rel, ed, q, k, kk, start, counts, out, N);
}

// Round 13
// 337.103 us; speedup vs baseline: 1.8159x; 1.1563x over previous
//
#include <hip/hip_runtime.h>

#define HH 4
#define FF 128
#define DD 32

typedef float f32x4 __attribute__((ext_vector_type(4)));
typedef _Float16 h16x8 __attribute__((ext_vector_type(8)));
typedef _Float16 h16x4 __attribute__((ext_vector_type(4)));
typedef _Float16 h16x2 __attribute__((ext_vector_type(2)));

// ---------------- prep: zero counts + fp16 weight tables ----------------
// wqT/wkT: [c][f] (c = h*32+d out-col, f = k-dim)  -> B-frags contiguous 16B
// wkD    : [h][f][d] plain fp16 copy of wk         -> kk B-frags contiguous

__global__ __launch_bounds__(256) void prep_kernel(
    const float* __restrict__ wq, const float* __restrict__ wk,
    _Float16* __restrict__ wqT, _Float16* __restrict__ wkT,
    _Float16* __restrict__ wkD, int* __restrict__ counts, int N) {
    int i = blockIdx.x * 256 + threadIdx.x;
    if (i < 16384) {
        int c = i >> 7, f = i & 127;
        int h = c >> 5, d = c & 31;
        wqT[i] = (_Float16)wq[h * 4096 + f * 32 + d];
        wkT[i] = (_Float16)wk[h * 4096 + f * 32 + d];
        wkD[i] = (_Float16)wk[i];
    }
    if (i < N + 2) counts[i] = 0;
}

// ---------------- scatter (sort) ----------------

__global__ void scatter_kernel(const int* __restrict__ src, const int* __restrict__ dst,
                               int* __restrict__ cursor, int2* __restrict__ ed, int E) {
    int i = blockIdx.x * blockDim.x + threadIdx.x;
    if (i >= E) return;
    int s = src[i];
    int pos = atomicAdd(&cursor[s], 1);
    long long pack = (unsigned)i | ((long long)dst[i] << 32);
    __builtin_nontemporal_store(pack, (long long*)&ed[pos]);
}

// ---------------- fused: q+k projection via MFMA + histogram ----------------
// Wave = 16 entities. A: lane row=l&15, k=(l>>4)*8+j from feat (fp32->fp16).
// B: lane col=l&15, k=(l>>4)*8+j from wqT/wkT (16B contiguous, L1-hot).
// C/D: col=l&15, row=(l>>4)*4+r  [m89-verified]. Output layout = [n][h*32+d].

__global__ __launch_bounds__(256) void qk_mfma_hist(
    const float* __restrict__ feat, const _Float16* __restrict__ wqT,
    const _Float16* __restrict__ wkT, _Float16* __restrict__ q16,
    _Float16* __restrict__ k16, int N,
    const int* __restrict__ src, int* __restrict__ counts, int E, int QKB) {
    int bid = blockIdx.x;
    if (bid >= QKB) {           // ---- histogram role ----
        int i = ((bid - QKB) * 256 + threadIdx.x) * 4;
        if (i + 3 < E) {
            int4 v = *(const int4*)(src + i);
            atomicAdd(&counts[v.x], 1);
            atomicAdd(&counts[v.y], 1);
            atomicAdd(&counts[v.z], 1);
            atomicAdd(&counts[v.w], 1);
        } else {
            for (; i < E; ++i) atomicAdd(&counts[src[i]], 1);
        }
        return;
    }
    int wid = threadIdx.x >> 6, lane = threadIdx.x & 63;
    int n0 = bid * 64 + wid * 16;
    if (n0 >= N) return;
    int lrow = lane & 15, lk = lane >> 4;
    int arow = n0 + lrow; if (arow >= N) arow = N - 1;

    f32x4 accq[8], acck[8];
#pragma unroll
    for (int t = 0; t < 8; ++t) { accq[t] = (f32x4){0.f,0.f,0.f,0.f}; acck[t] = (f32x4){0.f,0.f,0.f,0.f}; }

#pragma unroll
    for (int ks = 0; ks < 4; ++ks) {
        const float* ap = feat + (size_t)arow * FF + ks * 32 + lk * 8;
        h16x8 a;
#pragma unroll
        for (int j = 0; j < 8; ++j) a[j] = (_Float16)ap[j];
#pragma unroll
        for (int t = 0; t < 8; ++t) {
            const _Float16* bq = wqT + (size_t)(t * 16 + lrow) * FF + ks * 32 + lk * 8;
            const _Float16* bk = wkT + (size_t)(t * 16 + lrow) * FF + ks * 32 + lk * 8;
            h16x8 b1 = *(const h16x8*)bq;
            h16x8 b2 = *(const h16x8*)bk;
            accq[t] = __builtin_amdgcn_mfma_f32_16x16x32_f16(a, b1, accq[t], 0, 0, 0);
            acck[t] = __builtin_amdgcn_mfma_f32_16x16x32_f16(a, b2, acck[t], 0, 0, 0);
        }
    }
#pragma unroll
    for (int r = 0; r < 4; ++r) {
        int n = n0 + lk * 4 + r;
        if (n < N) {
#pragma unroll
            for (int t = 0; t < 8; ++t) {
                q16[(size_t)n * FF + t * 16 + lrow] = (_Float16)accq[t][r];
                k16[(size_t)n * FF + t * 16 + lrow] = (_Float16)acck[t][r];
            }
        }
    }
}

// ---------------- fused: kk via MFMA + group-offset alloc ----------------
// Per head: A = k16[n][h*32 + k] (K=32, one step), B = wkD[h][f][d] tiles.

__global__ __launch_bounds__(256) void kk_alloc_kernel(
    const _Float16* __restrict__ k16, const _Float16* __restrict__ wkD,
    _Float16* __restrict__ kk16, int N,
    const int* __restrict__ counts, int* __restrict__ startb,
    int* __restrict__ cursor, int* __restrict__ gcur, int KKB) {
    int bid = blockIdx.x;
    if (bid >= KKB) {           // ---- alloc role: wave scan + one atomic ----
        int sid = (bid - KKB) * 256 + threadIdx.x;
        int lane = threadIdx.x & 63;
        int cnt = (sid < N) ? counts[sid] : 0;
        int incl = cnt;
#pragma unroll
        for (int off = 1; off < 64; off <<= 1) {
            int y = __shfl_up(incl, off, 64);
            if (lane >= off) incl += y;
        }
        int total = __shfl(incl, 63, 64);
        int base = 0;
        if (lane == 63) base = atomicAdd(gcur, total);
        base = __shfl(base, 63, 64);
        if (sid < N) {
            int st = base + incl - cnt;
            startb[sid] = st;
            cursor[sid] = st;
        }
        return;
    }
    int wid = threadIdx.x >> 6, lane = threadIdx.x & 63;
    int n0 = bid * 64 + wid * 16;
    if (n0 >= N) return;
    int lrow = lane & 15, lk = lane >> 4;
    int arow = n0 + lrow; if (arow >= N) arow = N - 1;

#pragma unroll
    for (int h = 0; h < HH; ++h) {
        h16x8 a = *(const h16x8*)(k16 + (size_t)arow * FF + h * 32 + lk * 8);
        f32x4 acc[8];
#pragma unroll
        for (int t = 0; t < 8; ++t) acc[t] = (f32x4){0.f,0.f,0.f,0.f};
#pragma unroll
        for (int t = 0; t < 8; ++t) {
            h16x8 b = *(const h16x8*)(wkD + (size_t)h * 4096 + (size_t)(t * 16 + lrow) * 32 + lk * 8);
            acc[t] = __builtin_amdgcn_mfma_f32_16x16x32_f16(a, b, acc[t], 0, 0, 0);
        }
#pragma unroll
        for (int r = 0; r < 4; ++r) {
            int n = n0 + lk * 4 + r;
            if (n < N) {
#pragma unroll
                for (int t = 0; t < 8; ++t)
                    kk16[(size_t)n * 512 + h * FF + t * 16 + lrow] = (_Float16)acc[t][r];
            }
        }
    }
}

// ---------------- group kernel: unchanged r12 (fp16 k/kk/q) ----------------

__device__ __forceinline__ void score_row(   // slow-path helper
    const float* __restrict__ rel, const _Float16* __restrict__ k,
    int e_i, int dd, int t,
    const float4* kkA, const float4* kkB, const float2* qv, float* ev) {
    const float* rp = rel + (size_t)e_i * FF + t * 8;
    f32x4 r0 = __builtin_nontemporal_load((const f32x4*)rp);
    f32x4 r1 = __builtin_nontemporal_load((const f32x4*)(rp + 4));
#pragma unroll
    for (int h = 0; h < HH; ++h) {
        h16x2 kvh = *(const h16x2*)(k + ((size_t)dd * HH + h) * DD + t * 2);
        float a = r0.x * kkA[h].x + r0.y * kkA[h].y + r0.z * kkA[h].z + r0.w * kkA[h].w
                + r1.x * kkB[h].x + r1.y * kkB[h].y + r1.z * kkB[h].z + r1.w * kkB[h].w
                + qv[h].x * (float)kvh.x + qv[h].y * (float)kvh.y;
#pragma unroll
        for (int off = 1; off < 16; off <<= 1) a += __shfl_xor(a, off, 64);
        ev[h] = a >= 0.f ? a : 0.01f * a;
    }
}

__global__ __launch_bounds__(256) void group_kernel(
    const float* __restrict__ rel, const int2* __restrict__ ed,
    const _Float16* __restrict__ q, const _Float16* __restrict__ k,
    const _Float16* __restrict__ kk, const int* __restrict__ start,
    const int* __restrict__ counts, float* __restrict__ out, int N) {
    __shared__ __align__(16) float e_buf_all[4][128][4];
    int wid = threadIdx.x >> 6;
    int s = blockIdx.x * 4 + wid;
    if (s >= N) return;
    int cnt = counts[s];
    if (cnt == 0) return;
    int base = start[s];
    int lane = threadIdx.x & 63;
    int g = lane >> 4, t = lane & 15;
    int hsel = ((t & 1) << 1) | ((t & 2) >> 1);
    float (*e_buf)[4] = e_buf_all[wid];

    float4 kkA[HH], kkB[HH];
    float2 qv[HH];
    const _Float16* kkbase = kk + (size_t)s * (HH * FF) + t * 8;
    const _Float16* qbase  = q  + (size_t)s * (HH * DD) + t * 2;
#pragma unroll
    for (int h = 0; h < HH; ++h) {
        h16x4 a = *(const h16x4*)(kkbase + h * FF);
        h16x4 b = *(const h16x4*)(kkbase + h * FF + 4);
        kkA[h] = make_float4((float)a.x, (float)a.y, (float)a.z, (float)a.w);
        kkB[h] = make_float4((float)b.x, (float)b.y, (float)b.z, (float)b.w);
        h16x2 qh = *(const h16x2*)(qbase + h * DD);
        qv[h] = make_float2((float)qh.x, (float)qh.y);
    }

    float mloc = -INFINITY;
    bool fast = (cnt <= 128);

    for (int c0 = 0; c0 < cnt; c0 += 64) {
        int nc = min(cnt - c0, 64);
        int pv = 0, dv = 0;
        if (lane < nc) { int2 pd = ed[base + c0 + lane]; pv = pd.x; dv = pd.y; }
        for (int j0 = 0; j0 < nc; j0 += 4) {
            int idx = j0 + g;
            int sel = idx < nc ? idx : 0;
            int e_i = __shfl(pv, sel, 64);
            int dd  = __shfl(dv, sel, 64);
            const float* rp = rel + (size_t)e_i * FF + t * 8;
            f32x4 r0 = __builtin_nontemporal_load((const f32x4*)rp);
            f32x4 r1 = __builtin_nontemporal_load((const f32x4*)(rp + 4));
            float p[HH];
#pragma unroll
            for (int h = 0; h < HH; ++h) {
                h16x2 kvh = *(const h16x2*)(k + ((size_t)dd * HH + h) * DD + t * 2);
                p[h] = r0.x * kkA[h].x + r0.y * kkA[h].y + r0.z * kkA[h].z + r0.w * kkA[h].w
                     + r1.x * kkB[h].x + r1.y * kkB[h].y + r1.z * kkB[h].z + r1.w * kkB[h].w
                     + qv[h].x * (float)kvh.x + qv[h].y * (float)kvh.y;
            }
            float sx = (t & 1) ? p[0] : p[2];
            float sy = (t & 1) ? p[1] : p[3];
            float rx = __shfl_xor(sx, 1, 64);
            float ry = __shfl_xor(sy, 1, 64);
            float a0 = ((t & 1) ? p[2] : p[0]) + rx;
            float a1 = ((t & 1) ? p[3] : p[1]) + ry;
            float sz = (t & 2) ? a0 : a1;
            float rz = __shfl_xor(sz, 2, 64);
            float e = ((t & 2) ? a1 : a0) + rz;
            e += __shfl_xor(e, 4, 64);
            e += __shfl_xor(e, 8, 64);
            e = e >= 0.f ? e : 0.01f * e;
            if (idx < nc) {
                mloc = fmaxf(mloc, e);
                if (fast && t < 4) e_buf[c0 + idx][hsel] = e;
            }
        }
    }
    mloc = fmaxf(mloc, __shfl_xor(mloc, 16, 64));
    mloc = fmaxf(mloc, __shfl_xor(mloc, 32, 64));
    float m[HH];
    m[0] = __shfl(mloc, 0, 64);
    m[1] = __shfl(mloc, 2, 64);
    m[2] = __shfl(mloc, 1, 64);
    m[3] = __shfl(mloc, 3, 64);

    if (fast) {
        int i0 = lane, i1 = lane + 64;
        float ex0[HH] = {0.f, 0.f, 0.f, 0.f}, ex1[HH] = {0.f, 0.f, 0.f, 0.f};
        if (i0 < cnt) {
            float4 ev = *(const float4*)e_buf[i0];
            ex0[0] = __expf(ev.x - m[0]); ex0[1] = __expf(ev.y - m[1]);
            ex0[2] = __expf(ev.z - m[2]); ex0[3] = __expf(ev.w - m[3]);
        }
        if (i1 < cnt) {
            float4 ev = *(const float4*)e_buf[i1];
            ex1[0] = __expf(ev.x - m[0]); ex1[1] = __expf(ev.y - m[1]);
            ex1[2] = __expf(ev.z - m[2]); ex1[3] = __expf(ev.w - m[3]);
        }
        float rl[HH];
#pragma unroll
        for (int h = 0; h < HH; ++h) {
            float v = ex0[h] + ex1[h];
#pragma unroll
            for (int off = 1; off < 64; off <<= 1) v += __shfl_xor(v, off, 64);
            rl[h] = 1.0f / v;
        }
        if (i0 < cnt)
            out[ed[base + i0].x] = 0.25f * (ex0[0]*rl[0] + ex0[1]*rl[1] + ex0[2]*rl[2] + ex0[3]*rl[3]);
        if (i1 < cnt)
            out[ed[base + i1].x] = 0.25f * (ex1[0]*rl[0] + ex1[1]*rl[1] + ex1[2]*rl[2] + ex1[3]*rl[3]);
    } else {
        float lacc[HH] = {0.f, 0.f, 0.f, 0.f};
        for (int c0 = 0; c0 < cnt; c0 += 64) {
            int nc = min(cnt - c0, 64);
            int pv = 0, dv = 0;
            if (lane < nc) { int2 pd = ed[base + c0 + lane]; pv = pd.x; dv = pd.y; }
            for (int j0 = 0; j0 < nc; j0 += 4) {
                int idx = j0 + g;
                int sel = idx < nc ? idx : 0;
                int e_i = __shfl(pv, sel, 64);
                int dd  = __shfl(dv, sel, 64);
                float ev[HH];
                score_row(rel, k, e_i, dd, t, kkA, kkB, qv, ev);
                if (idx < nc && t == 0) {
#pragma unroll
                    for (int h = 0; h < HH; ++h) lacc[h] += __expf(ev[h] - m[h]);
                }
            }
        }
        float rl[HH];
#pragma unroll
        for (int h = 0; h < HH; ++h) {
            float v = lacc[h];
#pragma unroll
            for (int off = 1; off < 64; off <<= 1) v += __shfl_xor(v, off, 64);
            rl[h] = 1.0f / v;
        }
        for (int c0 = 0; c0 < cnt; c0 += 64) {
            int nc = min(cnt - c0, 64);
            int pv = 0, dv = 0;
            if (lane < nc) { int2 pd = ed[base + c0 + lane]; pv = pd.x; dv = pd.y; }
            for (int j0 = 0; j0 < nc; j0 += 4) {
                int idx = j0 + g;
                int sel = idx < nc ? idx : 0;
                int e_i = __shfl(pv, sel, 64);
                int dd  = __shfl(dv, sel, 64);
                float ev[HH];
                score_row(rel, k, e_i, dd, t, kkA, kkB, qv, ev);
                if (idx < nc && t == 0) {
                    float a = __expf(ev[0]-m[0])*rl[0] + __expf(ev[1]-m[1])*rl[1]
                            + __expf(ev[2]-m[2])*rl[2] + __expf(ev[3]-m[3])*rl[3];
                    out[e_i] = 0.25f * a;
                }
            }
        }
    }
}

extern "C" void kernel_launch(void* const* d_in, const int* in_sizes, int n_in,
                              void* d_out, int out_size, void* d_ws, size_t ws_size,
                              hipStream_t stream) {
    const float* feat = (const float*)d_in[0];   // (N,1,F)
    const float* rel  = (const float*)d_in[1];   // (E,1,F)
    const int*   src  = (const int*)d_in[2];
    const int*   dst  = (const int*)d_in[3];
    const float* wq   = (const float*)d_in[4];   // (H,F,D)
    const float* wk   = (const float*)d_in[5];
    float* out = (float*)d_out;

    const int N = in_sizes[0] / FF;
    const int E = in_sizes[2];

    _Float16* q16  = (_Float16*)d_ws;                 // N*128
    _Float16* k16  = q16 + (size_t)N * FF;            // N*128
    _Float16* kk16 = k16 + (size_t)N * FF;            // N*512
    _Float16* wqT  = kk16 + (size_t)N * 512;          // 16384
    _Float16* wkT  = wqT + 16384;                     // 16384
    _Float16* wkD  = wkT + 16384;                     // 16384
    int* counts    = (int*)(wkD + 16384);             // N
    int* gcur      = counts + N;                      // 1 (+1 pad)
    int* start     = gcur + 2;                        // N
    int* cursor    = start + N;                       // N
    int2* ed       = (int2*)(cursor + N);             // E

    int nb   = (N + 255) / 256;
    int QKB  = (N + 63) / 64;
    int HB   = (E + 1023) / 1024;
    int KKB  = (N + 63) / 64;
    int PREP = 16384 > N + 2 ? (16384 + 255) / 256 : (N + 2 + 255) / 256;

    prep_kernel<<<PREP, 256, 0, stream>>>(wq, wk, wqT, wkT, wkD, counts, N);
    qk_mfma_hist<<<QKB + HB, 256, 0, stream>>>(feat, wqT, wkT, q16, k16, N, src, counts, E, QKB);
    kk_alloc_kernel<<<KKB + nb, 256, 0, stream>>>(k16, wkD, kk16, N, counts, start, cursor, gcur, KKB);
    scatter_kernel<<<(E + 255) / 256, 256, 0, stream>>>(src, dst, cursor, ed, E);
    group_kernel<<<(N + 3) / 4, 256, 0, stream>>>(rel, ed, q16, k16, kk16, start, counts, out, N);
}